// Round 13
// baseline (411.771 us; speedup 1.0000x reference)
//
#include <hip/hip_runtime.h>
#include <stdint.h>

// FSUMGUCell: hy = (1-fg)*ng + fg*hx
//   fg = ( [hx|x]@w_f^T + b_f + 1 ) * 0.5
//   ng =   [fg*hx|x]@w_n^T + b_n
// B=H=I=2048, K=H+I=4096. bf16 MFMA path.
//
// Round 13 = Round 10 with two bugs fixed:
//  BUG1: ticket zeroing used threadIdx.x<512 with blockDim=256 -> GEMM2's
//        tickets never zeroed -> both blocks took winner path -> garbage.
//        Fix: block 0 zeros tickets[tid] and tickets[tid+256].
//  BUG2: GEMM2 had P0/OUT both = d_out while __restrict__ -> UB reorder
//        hazard. Fix: no __restrict__ on P0/P1/OUT.
// Core: r9-verified split-K (grid 512 = 256 tiles x 2 kparts, 4-wave 128x128,
// BK=64 dbuf, counted vmcnt(8), 2 blocks/CU, 40us). Fixup: both blocks store
// partials; release-fence + device-scope ticket atomicAdd; first arrival
// (loser) exits (GEMM1 losers convert Wn slice 'tile'); second (winner)
// acquire-fences, reads partner partial, runs fused epilogue. v = own_acc +
// partner + bias is the same f32 add either way -> bit-deterministic.

#define Hdim 2048
#define Idim 2048
#define Bdim 2048
#define Ktot 4096
#define KHALF 2048
#define NSTEP (KHALF / 64)   // 32

typedef __bf16 bf16;
typedef __bf16 bf16x8 __attribute__((ext_vector_type(8)));
typedef float  f32x4  __attribute__((ext_vector_type(4)));

__device__ __forceinline__ void gload_lds16(const bf16* g, bf16* l) {
  __builtin_amdgcn_global_load_lds(
      (const __attribute__((address_space(1))) unsigned int*)g,
      (__attribute__((address_space(3))) unsigned int*)l,
      16, 0, 0);
}

__device__ __forceinline__ void cvt8(const float* __restrict__ src, bf16* __restrict__ dst) {
  const float4* s = (const float4*)src;
  float4 a = s[0], b = s[1];
  bf16x8 o;
  o[0]=(bf16)a.x; o[1]=(bf16)a.y; o[2]=(bf16)a.z; o[3]=(bf16)a.w;
  o[4]=(bf16)b.x; o[5]=(bf16)b.y; o[6]=(bf16)b.z; o[7]=(bf16)b.w;
  *(bf16x8*)dst = o;
}

// ---- prep: Wf cvt | A1 = [hx|x] cvt | zero 512 tickets (Wn by gemm1 losers)
__global__ void prep_kernel(const float* __restrict__ w_f,
                            const float* __restrict__ hx, const float* __restrict__ x,
                            bf16* __restrict__ Wf, bf16* __restrict__ A1,
                            int* __restrict__ tickets) {
  if (blockIdx.x == 0) {                       // BUG1 fix: blockDim=256 -> 2 each
    tickets[threadIdx.x] = 0;
    tickets[threadIdx.x + 256] = 0;
  }
  const int n8 = Hdim * Ktot / 8;
  int stride = gridDim.x * blockDim.x;
  for (int i = blockIdx.x * blockDim.x + threadIdx.x; i < 2 * n8; i += stride) {
    if (i < n8) {
      cvt8(w_f + (size_t)i * 8, Wf + (size_t)i * 8);
    } else {
      int j = i - n8;
      int e = j * 8;
      int b = e >> 12;            // / 4096
      int k = e & (Ktot - 1);
      const float* src = (k < Hdim) ? (hx + (size_t)b * Hdim + k)
                                    : (x  + (size_t)b * Idim + (k - Hdim));
      cvt8(src, A1 + (size_t)e);
    }
  }
}

// ---- 128x128 x K=2048 partial GEMM + fused split-K fixup, 4 waves ----
// grid 512: bid = tile*2 + kpart. Core identical to r9 (verified 40us).
// LDS [2 buf][A|B][128*64] bf16 = 64 KB; 16B-chunk XOR swizzle: LDS[row][c]
// holds global chunk c ^ (row&7), staged via inverse-swizzled global source
// (global_load_lds writes linearly); read applies the same XOR.
template<int EPI>
__global__ __launch_bounds__(256)
void gemm_kernel(const bf16* __restrict__ Ab0, int sA0,
                 const bf16* __restrict__ Ab1, int sA1,
                 const bf16* __restrict__ W,
                 const float* __restrict__ bias,
                 const float* __restrict__ hx,      // EPI0 only
                 const float* __restrict__ wn_src,  // EPI0: Wn f32 (loser-convert)
                 bf16* __restrict__ wn_dst,         // EPI0
                 bf16* __restrict__ OMF,            // EPI0: write ; EPI1: read
                 bf16* __restrict__ A2L,            // EPI0: write ; EPI1: read
                 float* P0, float* P1,              // NO restrict (P0 aliases OUT)
                 int* __restrict__ ticket,
                 float* OUT)                        // EPI1
{
  __shared__ bf16 lds[2][2][8192];   // [buf][A=0/B=1][128*64] = 64 KB
  __shared__ int s_old;

  int bid   = blockIdx.x;
  int tile  = bid >> 1;
  int kpart = bid & 1;
  int sbid = (tile & 7) * 32 + (tile >> 3);  // XCD swizzle on tile (256%8==0)
  int tm = sbid >> 4, tn = sbid & 15;

  int tid  = threadIdx.x;
  int sub = tid >> 6, lane = tid & 63;
  int wrow = (sub >> 1) * 64;   // 2x2 wave grid: 64x64 per wave
  int wcol = (sub & 1) * 64;
  int fr = lane & 15, fq = lane >> 4;
  int swz = fr & 7;

  // staging: 2048 16B chunks/step, 256 thr -> 8 loads/thr. Thread t, pass jj:
  // row = jj*32 + (t>>3), dest chunk t&7, source chunk (t&7)^(row&7).
  int srow = tid >> 3;
  int csrc = (tid & 7) ^ (srow & 7);

  const bf16* pA = (kpart == 0)
      ? Ab0 + (size_t)(tm * 128 + srow) * sA0 + csrc * 8
      : Ab1 + (size_t)(tm * 128 + srow) * sA1 + csrc * 8;
  const size_t strA = (kpart == 0) ? (size_t)sA0 : (size_t)sA1;
  const bf16* pB = W + (size_t)(tn * 128 + srow) * Ktot + csrc * 8 + kpart * KHALF;
  int lbase = sub * 512;                     // + jj*2048 ; gload adds lane*16B

#define STAGE(buf, koff) do {                                                  \
    _Pragma("unroll")                                                          \
    for (int jj = 0; jj < 4; ++jj) {                                           \
      gload_lds16(pA + (size_t)jj * 32 * strA + (koff), &lds[buf][0][jj * 2048 + lbase]); \
      gload_lds16(pB + (size_t)jj * 32 * Ktot + (koff), &lds[buf][1][jj * 2048 + lbase]); \
    }                                                                          \
  } while (0)

  f32x4 acc[4][4] = {};

  auto compute = [&](int buf) {
    #pragma unroll
    for (int kk = 0; kk < 2; ++kk) {
      bf16x8 af[4], bv[4];
      int ch = ((kk * 4 + fq) ^ swz) * 8;
      #pragma unroll
      for (int m = 0; m < 4; ++m)
        af[m] = *(const bf16x8*)&lds[buf][0][(wrow + m * 16 + fr) * 64 + ch];
      #pragma unroll
      for (int n = 0; n < 4; ++n)
        bv[n] = *(const bf16x8*)&lds[buf][1][(wcol + n * 16 + fr) * 64 + ch];
      __builtin_amdgcn_s_setprio(1);
      #pragma unroll
      for (int m = 0; m < 4; ++m)
        #pragma unroll
        for (int n = 0; n < 4; ++n)
          acc[m][n] = __builtin_amdgcn_mfma_f32_16x16x32_bf16(af[m], bv[n], acc[m][n], 0, 0, 0);
      __builtin_amdgcn_s_setprio(0);
    }
  };

  STAGE(0, 0);
  int cur = 0;
  for (int t = 0; t < NSTEP - 1; ++t) {
    STAGE(cur ^ 1, (t + 1) * 64);                      // prefetch next K-tile
    asm volatile("s_waitcnt vmcnt(8)" ::: "memory");   // cur's 8 done; next 8 fly
    __builtin_amdgcn_s_barrier();
    compute(cur);
    __builtin_amdgcn_s_barrier();                      // reads done -> buf reusable
    cur ^= 1;
  }
  asm volatile("s_waitcnt vmcnt(0)" ::: "memory");
  __builtin_amdgcn_s_barrier();
  compute(cur);
#undef STAGE

  // ---- partial store. C/D layout: col = lane&15, row = (lane>>4)*4+i [m89] --
  float* Pme = kpart ? P1 : P0;
  int row0 = tm * 128 + wrow + fq * 4;
  int col0 = tn * 128 + wcol + fr;
  #pragma unroll
  for (int n = 0; n < 4; ++n)
    #pragma unroll
    for (int m = 0; m < 4; ++m)
      #pragma unroll
      for (int i = 0; i < 4; ++i)
        Pme[(size_t)(row0 + m * 16 + i) * Hdim + col0 + n * 16] = acc[m][n][i];

  // ---- ticket: release my partial; second arrival combines ----
  __threadfence();                       // release (device scope)
  __syncthreads();                       // all threads' stores fenced
  if (tid == 0) s_old = atomicAdd(ticket + tile, 1);
  __syncthreads();
  if (s_old == 0) {
    if (EPI == 0) {                      // loser converts Wn slice 'tile'
      const int CH = (Hdim * Ktot / 8) / 256;   // 4096 chunks per slice
      size_t base = (size_t)tile * CH;
      for (int c = tid; c < CH; c += 256)
        cvt8(wn_src + (base + c) * 8, wn_dst + (base + c) * 8);
    }
    return;
  }
  __threadfence();                       // acquire partner's partial

  const float* Po = kpart ? P0 : P1;
  #pragma unroll
  for (int n = 0; n < 4; ++n) {
    int gcol = col0 + n * 16;
    float bv2 = bias[gcol];
    #pragma unroll
    for (int m = 0; m < 4; ++m) {
      #pragma unroll
      for (int i = 0; i < 4; ++i) {
        int grow = row0 + m * 16 + i;
        size_t idx = (size_t)grow * Hdim + gcol;
        float v = acc[m][n][i] + Po[idx] + bv2;   // commutative -> deterministic
        if (EPI == 0) {
          float fg = (v + 1.0f) * 0.5f;
          OMF[idx] = (bf16)(1.0f - fg);
          A2L[idx] = (bf16)(fg * hx[idx]);
        } else {
          OUT[idx] = (float)OMF[idx] * v + (float)A2L[idx];  // (1-fg)*ng + fg*hx
        }
      }
    }
  }
}

extern "C" void kernel_launch(void* const* d_in, const int* in_sizes, int n_in,
                              void* d_out, int out_size, void* d_ws, size_t ws_size,
                              hipStream_t stream) {
  const float* x   = (const float*)d_in[0];
  const float* hx  = (const float*)d_in[1];
  const float* w_f = (const float*)d_in[2];
  const float* b_f = (const float*)d_in[3];
  const float* w_n = (const float*)d_in[4];
  const float* b_n = (const float*)d_in[5];
  float* out = (float*)d_out;

  bf16* A1  = (bf16*)d_ws;                         // [2048][4096] = 16 MB
  bf16* A2L = A1  + (size_t)Bdim * Ktot;           // [2048][2048] =  8 MB
  bf16* Wf  = A2L + (size_t)Bdim * KHALF;          // [2048][4096] = 16 MB
  bf16* Wn  = Wf  + (size_t)Hdim * Ktot;           // [2048][4096] = 16 MB
  bf16* OMF = Wn  + (size_t)Hdim * Ktot;           // [2048][2048] =  8 MB
  float* P1 = (float*)(OMF + (size_t)Bdim * Hdim); // [2048][2048] f32 = 16 MB
  int* tickets = (int*)(P1 + (size_t)Bdim * Hdim); // 512 ints
  float* P0 = out;                                 // kpart0 partials live in d_out
  // ws total ~80 MB

  prep_kernel<<<2048, 256, 0, stream>>>(w_f, hx, x, Wf, A1, tickets);

  // GEMM1: A = A1 both K-halves; fixup -> OMF + A2L; losers convert Wn.
  gemm_kernel<0><<<512, 256, 0, stream>>>(A1, Ktot, A1 + KHALF, Ktot, Wf, b_f,
                                          hx, w_n, Wn, OMF, A2L,
                                          P0, P1, tickets, nullptr);
  // GEMM2: A kpart0 = A2L (fg*hx), kpart1 = A1 right half (x); fixup -> hy.
  gemm_kernel<1><<<512, 256, 0, stream>>>(A2L, KHALF, A1 + Hdim, Ktot, Wn, b_n,
                                          nullptr, nullptr, nullptr, OMF, A2L,
                                          P0, P1, tickets + 256, out);
}

// Round 14
// 115.141 us; speedup vs baseline: 3.5762x; 3.5762x over previous
//
#include <hip/hip_runtime.h>
#include <stdint.h>

// FSUMGUCell: hy = (1-fg)*ng + fg*hx
//   fg = ( [hx|x]@w_f^T + b_f + 1 ) * 0.5
//   ng =   [fg*hx|x]@w_n^T + b_n
// B=H=I=2048, K=H+I=4096. bf16 MFMA path.
//
// Round 14 = r11 (best, 112.9us) with TRIPLE-buffered LDS -> 1 barrier/step.
// 3 bufs x 24KB = 72KB, 2 blocks/CU. Per step: vmcnt(6) [stage(t) landed,
// stage(t+1) in flight = 2-step latency cover] -> barrier [publishes stage(t);
// also proves step t-1's reads retired, so stage(t+2) may overwrite that
// buffer] -> STAGE(t+2) -> compute(t). Buffer rotation via 3 named pointers
// (no runtime-indexed arrays). Final step vmcnt(0) (only 6 outstanding there,
// vmcnt(6) would pass vacuously). Cross-block combine abandoned for good:
// r13 proved fences correct but L2-trashing (185us tail).

#define Hdim 2048
#define Idim 2048
#define Bdim 2048
#define Ktot 4096
#define KHALF 2048
#define NSTEP 64            // Ktot / 64
#define NSTEP2 32           // K-half boundary in BK units

typedef __bf16 bf16;
typedef __bf16 bf16x8 __attribute__((ext_vector_type(8)));
typedef float  f32x4  __attribute__((ext_vector_type(4)));

__device__ __forceinline__ void gload_lds16(const bf16* g, bf16* l) {
  __builtin_amdgcn_global_load_lds(
      (const __attribute__((address_space(1))) unsigned int*)g,
      (__attribute__((address_space(3))) unsigned int*)l,
      16, 0, 0);
}

__device__ __forceinline__ void cvt8(const float* __restrict__ src, bf16* __restrict__ dst) {
  const float4* s = (const float4*)src;
  float4 a = s[0], b = s[1];
  bf16x8 o;
  o[0]=(bf16)a.x; o[1]=(bf16)a.y; o[2]=(bf16)a.z; o[3]=(bf16)a.w;
  o[4]=(bf16)b.x; o[5]=(bf16)b.y; o[6]=(bf16)b.z; o[7]=(bf16)b.w;
  *(bf16x8*)dst = o;
}

// ---- fused prep: Wf cvt | Wn cvt | A1 = [hx|x] cvt (all f32 -> bf16 x8) ----
__global__ void prep_kernel(const float* __restrict__ w_f, const float* __restrict__ w_n,
                            const float* __restrict__ hx, const float* __restrict__ x,
                            bf16* __restrict__ Wf, bf16* __restrict__ Wn,
                            bf16* __restrict__ A1) {
  const int n8 = Hdim * Ktot / 8;
  int stride = gridDim.x * blockDim.x;
  for (int i = blockIdx.x * blockDim.x + threadIdx.x; i < 3 * n8; i += stride) {
    if (i < n8) {
      cvt8(w_f + (size_t)i * 8, Wf + (size_t)i * 8);
    } else if (i < 2 * n8) {
      int j = i - n8;
      cvt8(w_n + (size_t)j * 8, Wn + (size_t)j * 8);
    } else {
      int j = i - 2 * n8;
      int e = j * 8;
      int b = e >> 12;            // / 4096
      int k = e & (Ktot - 1);
      const float* src = (k < Hdim) ? (hx + (size_t)b * Hdim + k)
                                    : (x  + (size_t)b * Idim + (k - Hdim));
      cvt8(src, A1 + (size_t)e);
    }
  }
}

// ---- 128x64 x K=4096 GEMM, 4 waves, 3-buf LDS, 1 barrier/step, fused epi ----
// grid 512 = 16 tm x 32 tn. C[row][col] = sum_k A[row][k] * W[col][k].
// A K-halves: (Ab0,sA0) k<2048, (Ab1,sA1) k>=2048. LDS buf = [A 128x64 |
// B 64x64] bf16 = 24 KB; 16B-chunk XOR swizzle: LDS[row][c] holds global
// chunk c ^ (row&7), staged via inverse-swizzled global source
// (global_load_lds writes linearly); read applies the same XOR.
template<int EPI>
__global__ __launch_bounds__(256, 2)
void gemm_kernel(const bf16* __restrict__ Ab0, int sA0,
                 const bf16* __restrict__ Ab1, int sA1,
                 const bf16* __restrict__ W,
                 const float* __restrict__ bias,
                 const float* __restrict__ hx,   // EPI0 only
                 bf16* __restrict__ OMF,         // EPI0: write (1-fg) ; EPI1: read
                 bf16* __restrict__ A2L,         // EPI0: write bf16(fg*hx) ; EPI1: read
                 float* __restrict__ OUT)        // EPI1: write hy
{
  __shared__ bf16 lds[3][12288];   // [buf][ A:0..8191 | B:8192..12287 ] = 72 KB

  int bid  = blockIdx.x;
  int sbid = (bid & 7) * 64 + (bid >> 3);   // XCD swizzle (512%8==0, bijective)
  int tm = sbid >> 5, tn = sbid & 31;       // 16 x 32 tiles of 128x64

  int tid = threadIdx.x;
  int w = tid >> 6, lane = tid & 63;
  int wrow = (w >> 1) * 64;     // 2x2 wave grid over 128x64: 64x32 per wave
  int wcol = (w & 1) * 32;
  int fr = lane & 15, fq = lane >> 4;
  int swz = fr & 7;

  // staging: A 1024 + B 512 16B chunks/step, 256 thr -> 6 loads/thread.
  // Thread t: row = jj*32 + (t>>3), dest chunk t&7, src chunk (t&7)^(row&7).
  int srow = tid >> 3;                  // 0..31
  int csrc = (tid & 7) ^ (srow & 7);

  const bf16* pA0 = Ab0 + (size_t)(tm * 128 + srow) * sA0 + csrc * 8;
  const bf16* pA1 = Ab1 + (size_t)(tm * 128 + srow) * sA1 + csrc * 8;
  const bf16* pB  = W   + (size_t)(tn * 64  + srow) * Ktot + csrc * 8;
  int lb = w * 512;                     // wave-uniform LDS base; gload adds lane*16B

#define STAGE(pbuf, t_) do {                                                   \
    const bf16* pa_ = ((t_) < NSTEP2) ? pA0 : pA1;                             \
    size_t sa_ = ((t_) < NSTEP2) ? (size_t)sA0 : (size_t)sA1;                  \
    size_t ko_ = ((t_) < NSTEP2) ? (size_t)(t_) * 64 : (size_t)((t_) - NSTEP2) * 64; \
    _Pragma("unroll")                                                          \
    for (int jj = 0; jj < 4; ++jj)                                             \
      gload_lds16(pa_ + (size_t)jj * 32 * sa_ + ko_, (pbuf) + jj * 2048 + lb); \
    _Pragma("unroll")                                                          \
    for (int jj = 0; jj < 2; ++jj)                                             \
      gload_lds16(pB + (size_t)jj * 32 * Ktot + (size_t)(t_) * 64,             \
                  (pbuf) + 8192 + jj * 2048 + lb);                             \
  } while (0)

  f32x4 acc[4][2] = {};

#define COMPUTE(pbuf) do {                                                     \
    _Pragma("unroll")                                                          \
    for (int kk = 0; kk < 2; ++kk) {                                           \
      bf16x8 af[4], bv[2];                                                     \
      int ch = ((kk * 4 + fq) ^ swz) * 8;                                      \
      _Pragma("unroll")                                                        \
      for (int m = 0; m < 4; ++m)                                              \
        af[m] = *(const bf16x8*)((pbuf) + (wrow + m * 16 + fr) * 64 + ch);     \
      _Pragma("unroll")                                                        \
      for (int n = 0; n < 2; ++n)                                              \
        bv[n] = *(const bf16x8*)((pbuf) + 8192 + (wcol + n * 16 + fr) * 64 + ch); \
      __builtin_amdgcn_s_setprio(1);                                           \
      _Pragma("unroll")                                                        \
      for (int m = 0; m < 4; ++m)                                              \
        _Pragma("unroll")                                                      \
        for (int n = 0; n < 2; ++n)                                            \
          acc[m][n] = __builtin_amdgcn_mfma_f32_16x16x32_bf16(af[m], bv[n], acc[m][n], 0, 0, 0); \
      __builtin_amdgcn_s_setprio(0);                                           \
    }                                                                          \
  } while (0)

  bf16* p0 = &lds[0][0];
  bf16* p1 = &lds[1][0];
  bf16* p2 = &lds[2][0];

  STAGE(p0, 0);
  STAGE(p1, 1);
  #pragma unroll 1
  for (int t = 0; t < NSTEP; ++t) {
    if (t < NSTEP - 1) asm volatile("s_waitcnt vmcnt(6)" ::: "memory");
    else               asm volatile("s_waitcnt vmcnt(0)" ::: "memory");
    __builtin_amdgcn_s_barrier();        // stage(t) published; t-1 reads retired
    asm volatile("" ::: "memory");
    if (t + 2 < NSTEP) STAGE(p2, t + 2); // overwrites buffer last read at t-1
    COMPUTE(p0);
    bf16* tmp = p0; p0 = p1; p1 = p2; p2 = tmp;
  }
#undef COMPUTE
#undef STAGE

  // ---- fused epilogue. C/D layout: col = lane&15, row = (lane>>4)*4+i [m89]
  int row0 = tm * 128 + wrow + fq * 4;
  int col0 = tn * 64 + wcol + fr;
  #pragma unroll
  for (int n = 0; n < 2; ++n) {
    int gcol = col0 + n * 16;
    float bv2 = bias[gcol];
    #pragma unroll
    for (int m = 0; m < 4; ++m) {
      #pragma unroll
      for (int i = 0; i < 4; ++i) {
        int grow = row0 + m * 16 + i;
        size_t idx = (size_t)grow * Hdim + gcol;
        float v = acc[m][n][i] + bv2;
        if (EPI == 0) {
          float fg = (v + 1.0f) * 0.5f;
          OMF[idx] = (bf16)(1.0f - fg);
          A2L[idx] = (bf16)(fg * hx[idx]);
        } else {
          OUT[idx] = (float)OMF[idx] * v + (float)A2L[idx];  // (1-fg)*ng + fg*hx
        }
      }
    }
  }
}

extern "C" void kernel_launch(void* const* d_in, const int* in_sizes, int n_in,
                              void* d_out, int out_size, void* d_ws, size_t ws_size,
                              hipStream_t stream) {
  const float* x   = (const float*)d_in[0];
  const float* hx  = (const float*)d_in[1];
  const float* w_f = (const float*)d_in[2];
  const float* b_f = (const float*)d_in[3];
  const float* w_n = (const float*)d_in[4];
  const float* b_n = (const float*)d_in[5];
  float* out = (float*)d_out;

  bf16* A1  = (bf16*)d_ws;                         // [2048][4096] = 16 MB
  bf16* A2L = A1  + (size_t)Bdim * Ktot;           // [2048][2048] =  8 MB
  bf16* Wf  = A2L + (size_t)Bdim * KHALF;          // [2048][4096] = 16 MB
  bf16* Wn  = Wf  + (size_t)Hdim * Ktot;           // [2048][4096] = 16 MB
  bf16* OMF = Wn  + (size_t)Hdim * Ktot;           // [2048][2048] =  8 MB
  // ws total: 64 MB

  prep_kernel<<<2048, 256, 0, stream>>>(w_f, w_n, hx, x, Wf, Wn, A1);

  // GEMM1: A = A1 (both K-halves); fused epilogue -> OMF + A2L.
  gemm_kernel<0><<<512, 256, 0, stream>>>(A1, Ktot, A1 + KHALF, Ktot, Wf, b_f,
                                          hx, OMF, A2L, nullptr);
  // GEMM2: A = [A2L | A1 right half (x)]; fused epilogue -> hy.
  gemm_kernel<1><<<512, 256, 0, stream>>>(A2L, KHALF, A1 + Hdim, Ktot, Wn, b_n,
                                          nullptr, OMF, A2L, out);
}